// Round 2
// baseline (1000.145 us; speedup 1.0000x reference)
//
#include <hip/hip_runtime.h>
#include <math.h>

#define BB 8
#define CC 256
#define KK 19
#define HW 16384
#define HW4 4096            // HW / 4 (float4 units)

// ---- K1: contraction, map chunk staged in LDS, 2 channels per thread ----
// Round 5: round-1 K1 (1 ch/thread) was LDS-issue-bound: 608 ds_read_b128
// per wave x 16 waves/CU x ~12cyc = ~49us/CU, plus ~69MB of suspected
// scratch-spill write traffic (VGPR_Count=64 == exactly the live set).
// Now thread (c = t&127, h = t>>7) owns channels c and c+128 over half the
// hw-chunk: each mlds read feeds 8 FMAs instead of 4 -> per-wave LDS reads
// halve (608 -> 304) at unchanged occupancy (same grid, same 16 waves/CU).
// Staging is 4-deep per row (32 VGPRs live; total ~85) -> no spill at the
// 128-VGPR cap from __launch_bounds__(256,4).
#define CHUNK4 32           // float4 per chunk = 128 floats
#define NS (HW4 / CHUNK4)   // 128 chunks per batch

// Macro-unrolled k loops: guarantees literal acc indices -> SROA -> registers.
#define FOR_K(OP) OP(0) OP(1) OP(2) OP(3) OP(4) OP(5) OP(6) OP(7) OP(8) OP(9) \
                  OP(10) OP(11) OP(12) OP(13) OP(14) OP(15) OP(16) OP(17) OP(18)

__global__ __launch_bounds__(256, 4) void CGM_k1_contract(
    const float* __restrict__ feature,
    const float* __restrict__ map_,
    float* __restrict__ att,        // fallback path target (pre-zeroed)
    float* __restrict__ part)       // [KK][BB][NS][CC] partials, or nullptr
{
    const int bI = blockIdx.x;      // b*NS + s
    const int s  = bI & (NS - 1);
    const int b  = bI >> 7;         // NS == 128
    const int t  = threadIdx.x;
    const int c  = t & 127;         // channel low (also owns c+128)
    const int h  = t >> 7;          // hw half: i in [h*16, h*16+16)

    // 19456 B: first 9728 B alias the map tile; reused for the h-combine.
    __shared__ float smem[KK * 2 * 128];
    float4* mlds = (float4*)smem;          // [KK][CHUNK4]

    // Stage map chunk: 19 rows x 32 float4, coalesced (512 B runs per row).
    const float4* m4 = (const float4*)map_ + (size_t)b * KK * HW4 + s * CHUNK4;
    for (int idx = t; idx < KK * CHUNK4; idx += 256) {
        const int k = idx >> 5;
        const int j = idx & 31;
        mlds[idx] = m4[(size_t)k * HW4 + j];
    }
    __syncthreads();

    float accA[KK], accB[KK];
#define ZERO(K) accA[K] = 0.f; accB[K] = 0.f;
    FOR_K(ZERO)
#undef ZERO

    // Two feature rows per thread; 16 float4 each, 64B-line-granular staging.
    const float4* fA = (const float4*)feature
                     + (size_t)(b * CC + c) * HW4 + s * CHUNK4 + h * 16;
    const float4* fB = fA + (size_t)128 * HW4;

#pragma unroll 1
    for (int g = 0; g < 4; ++g) {          // 4 groups of 4 float4 per row
        float4 fa[4], fb[4];
#pragma unroll
        for (int u = 0; u < 4; ++u) { fa[u] = fA[g * 4 + u]; fb[u] = fB[g * 4 + u]; }
#pragma unroll
        for (int u = 0; u < 4; ++u) {
            const int i = h * 16 + g * 4 + u;
            const float4 av = fa[u];
            const float4 bv = fb[u];
            // mlds reads are same-address across the wave -> broadcast; each
            // read now feeds 8 FMAs (2 channels x 4 components).
#define STEP(K) { const float4 m = mlds[(K) * CHUNK4 + i]; \
                  accA[K] += av.x * m.x + av.y * m.y + av.z * m.z + av.w * m.w; \
                  accB[K] += bv.x * m.x + bv.y * m.y + bv.z * m.z + bv.w * m.w; }
            FOR_K(STEP)
#undef STEP
        }
    }

    // Combine the two hw-halves via LDS (reuses the map tile space).
    __syncthreads();                       // everyone done reading mlds
    if (h == 1) {
        // lanes c consecutive -> consecutive words -> 2-way alias only (free)
#define SPILL(K) { smem[(K) * 256 + c] = accA[K]; smem[(K) * 256 + 128 + c] = accB[K]; }
        FOR_K(SPILL)
#undef SPILL
    }
    __syncthreads();
    if (h == 0) {
        if (part) {
            // k-major layout [k][b][s][c]: each k-store is a coalesced 256B
            // wave store, and K1b later streams a contiguous 128KB per (b,k).
#define FIN(K) { const float s0 = accA[K] + smem[(K) * 256 + c]; \
                 const float s1 = accB[K] + smem[(K) * 256 + 128 + c]; \
                 float* d = part + ((size_t)((K) * BB + b) * NS + s) * CC; \
                 d[c] = s0; d[c + 128] = s1; }
            FOR_K(FIN)
#undef FIN
        } else {
            // Fallback: fp32 atomics into the 152 KB att buffer.
#define FIN(K) { const float s0 = accA[K] + smem[(K) * 256 + c]; \
                 const float s1 = accB[K] + smem[(K) * 256 + 128 + c]; \
                 atomicAdd(&att[(size_t)(b * CC + c) * KK + (K)], s0); \
                 atomicAdd(&att[(size_t)(b * CC + c + 128) * KK + (K)], s1); }
            FOR_K(FIN)
#undef FIN
        }
    }
}

// ---- K1b: fold the NS=128 hw-chunk partials into att. ----
// part[k][b][s][c] is contiguous per (b,k): each block streams 128 KB with
// float4 loads (1 KB per wave-load, fully coalesced), 4-way s-split across
// the 256 threads, 4 rotating accumulators for ILP, LDS tree at the end.
__global__ __launch_bounds__(256) void CGM_k1b_reduce(
    const float* __restrict__ part,
    float* __restrict__ att)
{
    const int bk = blockIdx.x;      // b*KK + k
    const int b  = bk / KK;
    const int k  = bk - b * KK;
    const int t  = threadIdx.x;
    const int q  = t & 63;          // float4 column: channels 4q..4q+3
    const int sg = t >> 6;          // s quarter: 32 rows

    const float4* p4 = (const float4*)(part + (size_t)(k * BB + b) * NS * CC)
                     + (size_t)(sg * 32) * 64 + q;

    float4 a0 = {0.f, 0.f, 0.f, 0.f}, a1 = a0, a2 = a0, a3 = a0;
#pragma unroll 2
    for (int i = 0; i < 32; i += 4) {
        const float4 v0 = p4[(size_t)(i + 0) * 64];
        const float4 v1 = p4[(size_t)(i + 1) * 64];
        const float4 v2 = p4[(size_t)(i + 2) * 64];
        const float4 v3 = p4[(size_t)(i + 3) * 64];
        a0.x += v0.x; a0.y += v0.y; a0.z += v0.z; a0.w += v0.w;
        a1.x += v1.x; a1.y += v1.y; a1.z += v1.z; a1.w += v1.w;
        a2.x += v2.x; a2.y += v2.y; a2.z += v2.z; a2.w += v2.w;
        a3.x += v3.x; a3.y += v3.y; a3.z += v3.z; a3.w += v3.w;
    }
    float4 r;
    r.x = (a0.x + a1.x) + (a2.x + a3.x);
    r.y = (a0.y + a1.y) + (a2.y + a3.y);
    r.z = (a0.z + a1.z) + (a2.z + a3.z);
    r.w = (a0.w + a1.w) + (a2.w + a3.w);

    __shared__ float4 red[4][64];
    red[sg][q] = r;
    __syncthreads();
    if (t < 64) {
        const float4 u0 = red[0][q], u1 = red[1][q], u2 = red[2][q], u3 = red[3][q];
        float4 o;
        o.x = (u0.x + u1.x) + (u2.x + u3.x);
        o.y = (u0.y + u1.y) + (u2.y + u3.y);
        o.z = (u0.z + u1.z) + (u2.z + u3.z);
        o.w = (u0.w + u1.w) + (u2.w + u3.w);
        float* d = att + ((size_t)b * CC + 4 * q) * KK + k;
        d[0 * KK] = o.x;
        d[1 * KK] = o.y;
        d[2 * KK] = o.z;
        d[3 * KK] = o.w;
    }
}

// ---- K2: gate + apply (round-2 structure, measured ~6.9 TB/s) ----
#define S2 8                 // hw splits
#define CT2 16               // channels per block
#define CHUNK24 (HW4 / S2)   // 512 float4

__global__ __launch_bounds__(256) void CGM_k2_apply(
    const float* __restrict__ feature,
    const float* __restrict__ gamma,
    const float* __restrict__ att,
    float* __restrict__ out)
{
    const int bI = blockIdx.x;
    const int ct = bI & 15;
    const int s  = (bI >> 4) & (S2 - 1);
    const int b  = bI >> 7;
    const int t  = threadIdx.x;
    const int c0 = ct * CT2;

    __shared__ float sgk[CT2 * KK];
    __shared__ float scale[CT2];

    // NOTE: CT2*KK = 304 > 256 threads — MUST be a strided loop, not `if`.
    for (int idx = t; idx < CT2 * KK; idx += 256) {
        const int c = idx / KK;
        const int k = idx - c * KK;
        const float a = att[(size_t)(b * CC + c0 + c) * KK + k];
        const float sig = 1.f / (1.f + __expf(-a));
        sgk[idx] = sig * gamma[k];
    }
    __syncthreads();

    if (t < CT2) {
        float ssum = 0.f;
#define ADDK(K) ssum += sgk[t * KK + (K)];
        FOR_K(ADDK)
#undef ADDK
        scale[t] = 1.f + ssum;
    }
    __syncthreads();

    const float4* f4 = (const float4*)feature + (size_t)(b * CC + c0) * HW4;
    float4*       o4 = (float4*)out           + (size_t)(b * CC + c0) * HW4;
    const int ibase = s * CHUNK24;
#pragma unroll
    for (int c = 0; c < CT2; ++c) {
        const float sc = scale[c];
#pragma unroll
        for (int r = 0; r < CHUNK24 / 256; ++r) {   // 2 iterations
            const int i = ibase + r * 256 + t;
            const float4 f = f4[(size_t)c * HW4 + i];
            float4 o;
            o.x = f.x * sc;
            o.y = f.y * sc;
            o.z = f.z * sc;
            o.w = f.w * sc;
            o4[(size_t)c * HW4 + i] = o;
        }
    }
}

extern "C" void kernel_launch(void* const* d_in, const int* in_sizes, int n_in,
                              void* d_out, int out_size, void* d_ws, size_t ws_size,
                              hipStream_t stream) {
    const float* feature = (const float*)d_in[0];
    const float* map_    = (const float*)d_in[1];
    const float* gamma   = (const float*)d_in[2];
    float* out           = (float*)d_out;
    float* att           = (float*)d_ws;   // BB*CC*KK*4 = 155,648 B

    const size_t att_bytes  = (size_t)BB * CC * KK * sizeof(float);
    const size_t part_off   = (att_bytes + 255) & ~(size_t)255;
    const size_t part_bytes = (size_t)KK * BB * NS * CC * sizeof(float); // 19,922,944 B
    const bool   split      = ws_size >= part_off + part_bytes;
    float* part = split ? (float*)((char*)d_ws + part_off) : nullptr;

    if (!split) {
        // att is re-poisoned to 0xAA before every launch — atomic fallback
        // needs it zeroed (hipMemsetAsync on stream is graph-capture safe).
        hipMemsetAsync(att, 0, att_bytes, stream);
    }

    const int grid1 = BB * NS;                // 1024
    CGM_k1_contract<<<grid1, 256, 0, stream>>>(feature, map_, att, part);

    if (split) {
        CGM_k1b_reduce<<<BB * KK, 256, 0, stream>>>(part, att);
    }

    const int grid2 = BB * S2 * (CC / CT2);   // 1024
    CGM_k2_apply<<<grid2, 256, 0, stream>>>(feature, gamma, att, out);
}

// Round 3
// 650.742 us; speedup vs baseline: 1.5369x; 1.5369x over previous
//
#include <hip/hip_runtime.h>
#include <math.h>

#define BB 8
#define CC 256
#define KK 19
#define HW 16384
#define HW4 4096            // HW / 4 (float4 units)

// ---- K1: contraction, map chunk in LDS, 4 channels per thread ----
// History:
//  r1 (1 ch/thread, VGPR=64): 93 us, LDS-issue-bound (608 ds_read_b128/wave)
//     + ~71 MB spill writes (acc[19]+f[8] didn't fit 64 regs).
//  r2 (2 ch/thread): compiler KEPT VGPR=64 (it targets 8 waves/EU on its own;
//     launch_bounds' 2nd arg is only a minimum) -> acc arrays lived in
//     scratch -> 2.5 GB scratch traffic, 798 us.
//  r3 (this): amdgpu_waves_per_eu(4,4) pins the budget at 128 VGPRs
//     (occupancy is grid-limited to 4 blocks/CU = 16 waves/CU anyway), and
//     4 ch/thread cuts per-wave LDS reads 608 -> 152. Live set ~110 < 128.
//     h-halves combined via LDS in k-chunks of 5 (all literal indices) so the
//     part buffer stays at the proven 19.9 MB layout; K1b/K2 unchanged.
#define CHUNK4 32           // float4 per chunk = 128 floats
#define NS (HW4 / CHUNK4)   // 128 chunks per batch

// Macro-unrolled k loops: guarantees literal acc indices -> SROA -> registers.
#define FOR_K(OP) OP(0) OP(1) OP(2) OP(3) OP(4) OP(5) OP(6) OP(7) OP(8) OP(9) \
                  OP(10) OP(11) OP(12) OP(13) OP(14) OP(15) OP(16) OP(17) OP(18)

__global__ __launch_bounds__(256)
__attribute__((amdgpu_waves_per_eu(4, 4)))
void CGM_k1_contract(
    const float* __restrict__ feature,
    const float* __restrict__ map_,
    float* __restrict__ att,        // fallback path target (pre-zeroed)
    float* __restrict__ part)       // [KK][BB][NS][CC] partials, or nullptr
{
    const int bI = blockIdx.x;      // b*NS + s
    const int s  = bI & (NS - 1);
    const int b  = bI >> 7;         // NS == 128
    const int t  = threadIdx.x;
    const int c  = t & 63;          // base channel; owns c, c+64, c+128, c+192
    const int h  = t >> 6;          // hw quarter (wave-uniform): i in [h*8, h*8+8)

    // 15360 B. First 9728 B = map tile [KK][CHUNK4] float4; after the main
    // loop the whole thing is reused as the h-combine buffer [3][5*4][64] f32.
    __shared__ float4 smem4[960];
    float4* mlds  = smem4;
    float*  smemf = (float*)smem4;

    // Stage map chunk: 19 rows x 32 float4, coalesced (512 B runs per row).
    const float4* m4 = (const float4*)map_ + (size_t)b * KK * HW4 + s * CHUNK4;
    for (int idx = t; idx < KK * CHUNK4; idx += 256) {
        const int k = idx >> 5;
        const int j = idx & 31;
        mlds[idx] = m4[(size_t)k * HW4 + j];
    }
    __syncthreads();

    float acc0[KK], acc1[KK], acc2[KK], acc3[KK];
#define ZERO(K) acc0[K] = 0.f; acc1[K] = 0.f; acc2[K] = 0.f; acc3[K] = 0.f;
    FOR_K(ZERO)
#undef ZERO

    // 4 feature rows per thread, 8 float4 each (this thread's hw quarter).
    const float4* fA = (const float4*)feature
                     + (size_t)(b * CC + c) * HW4 + s * CHUNK4 + h * 8;
    const float4* fB = fA + (size_t)64  * HW4;
    const float4* fC = fA + (size_t)128 * HW4;
    const float4* fD = fA + (size_t)192 * HW4;

#pragma unroll 1
    for (int u = 0; u < 8; ++u) {
        const int i = h * 8 + u;
        const float4 a0 = fA[u];
        const float4 a1 = fB[u];
        const float4 a2 = fC[u];
        const float4 a3 = fD[u];
        // mlds read is same-address across the wave -> broadcast; each read
        // feeds 16 FMAs (4 channels x 4 components).
#define STEP(K) { const float4 m = mlds[(K) * CHUNK4 + i]; \
                  acc0[K] += a0.x * m.x + a0.y * m.y + a0.z * m.z + a0.w * m.w; \
                  acc1[K] += a1.x * m.x + a1.y * m.y + a1.z * m.z + a1.w * m.w; \
                  acc2[K] += a2.x * m.x + a2.y * m.y + a2.z * m.z + a2.w * m.w; \
                  acc3[K] += a3.x * m.x + a3.y * m.y + a3.z * m.z + a3.w * m.w; }
        FOR_K(STEP)
#undef STEP
    }

    // ---- Combine the 4 hw quarters across waves, 5 k at a time. ----
    // Layout in smemf: [h-1][slot*4+j][c] -> (h-1)*1280 + (slot*4+j)*64 + c.
    // All indices into acc* are literals (SROA-safe). Branches are
    // wave-uniform (h is per-wave constant).
#define WR1(SL, K) { const int o = hb + ((SL) * 4) * 64 + c; \
    smemf[o]       = acc0[K]; smemf[o + 64]  = acc1[K]; \
    smemf[o + 128] = acc2[K]; smemf[o + 192] = acc3[K]; }

#define FIN1(SL, K) { const int o = ((SL) * 4) * 64 + c; \
    const float r0 = acc0[K] + smemf[o]       + smemf[1280 + o]       + smemf[2560 + o]; \
    const float r1 = acc1[K] + smemf[o + 64]  + smemf[1280 + o + 64]  + smemf[2560 + o + 64]; \
    const float r2 = acc2[K] + smemf[o + 128] + smemf[1280 + o + 128] + smemf[2560 + o + 128]; \
    const float r3 = acc3[K] + smemf[o + 192] + smemf[1280 + o + 192] + smemf[2560 + o + 192]; \
    if (part) { \
        float* d = part + ((size_t)((K) * BB + b) * NS + s) * CC + c; \
        d[0] = r0; d[64] = r1; d[128] = r2; d[192] = r3; \
    } else { \
        atomicAdd(&att[(size_t)(b * CC + c) * KK + (K)],       r0); \
        atomicAdd(&att[(size_t)(b * CC + c + 64) * KK + (K)],  r1); \
        atomicAdd(&att[(size_t)(b * CC + c + 128) * KK + (K)], r2); \
        atomicAdd(&att[(size_t)(b * CC + c + 192) * KK + (K)], r3); \
    } }

#define CHUNK5(Ka, Kb, Kc, Kd, Ke) \
    __syncthreads(); \
    if (h) { const int hb = (h - 1) * 1280; \
        WR1(0, Ka) WR1(1, Kb) WR1(2, Kc) WR1(3, Kd) WR1(4, Ke) } \
    __syncthreads(); \
    if (!h) { FIN1(0, Ka) FIN1(1, Kb) FIN1(2, Kc) FIN1(3, Kd) FIN1(4, Ke) }

#define CHUNK4T(Ka, Kb, Kc, Kd) \
    __syncthreads(); \
    if (h) { const int hb = (h - 1) * 1280; \
        WR1(0, Ka) WR1(1, Kb) WR1(2, Kc) WR1(3, Kd) } \
    __syncthreads(); \
    if (!h) { FIN1(0, Ka) FIN1(1, Kb) FIN1(2, Kc) FIN1(3, Kd) }

    CHUNK5(0, 1, 2, 3, 4)
    CHUNK5(5, 6, 7, 8, 9)
    CHUNK5(10, 11, 12, 13, 14)
    CHUNK4T(15, 16, 17, 18)

#undef WR1
#undef FIN1
#undef CHUNK5
#undef CHUNK4T
}

// ---- K1b: fold the NS=128 hw-chunk partials into att. ----
// part[k][b][s][c] is contiguous per (b,k): each block streams 128 KB with
// float4 loads (1 KB per wave-load, fully coalesced), 4-way s-split across
// the 256 threads, 4 rotating accumulators for ILP, LDS tree at the end.
// (Validated numerically in rounds 1-2.)
__global__ __launch_bounds__(256) void CGM_k1b_reduce(
    const float* __restrict__ part,
    float* __restrict__ att)
{
    const int bk = blockIdx.x;      // b*KK + k
    const int b  = bk / KK;
    const int k  = bk - b * KK;
    const int t  = threadIdx.x;
    const int q  = t & 63;          // float4 column: channels 4q..4q+3
    const int sg = t >> 6;          // s quarter: 32 rows

    const float4* p4 = (const float4*)(part + (size_t)(k * BB + b) * NS * CC)
                     + (size_t)(sg * 32) * 64 + q;

    float4 a0 = {0.f, 0.f, 0.f, 0.f}, a1 = a0, a2 = a0, a3 = a0;
#pragma unroll 2
    for (int i = 0; i < 32; i += 4) {
        const float4 v0 = p4[(size_t)(i + 0) * 64];
        const float4 v1 = p4[(size_t)(i + 1) * 64];
        const float4 v2 = p4[(size_t)(i + 2) * 64];
        const float4 v3 = p4[(size_t)(i + 3) * 64];
        a0.x += v0.x; a0.y += v0.y; a0.z += v0.z; a0.w += v0.w;
        a1.x += v1.x; a1.y += v1.y; a1.z += v1.z; a1.w += v1.w;
        a2.x += v2.x; a2.y += v2.y; a2.z += v2.z; a2.w += v2.w;
        a3.x += v3.x; a3.y += v3.y; a3.z += v3.z; a3.w += v3.w;
    }
    float4 r;
    r.x = (a0.x + a1.x) + (a2.x + a3.x);
    r.y = (a0.y + a1.y) + (a2.y + a3.y);
    r.z = (a0.z + a1.z) + (a2.z + a3.z);
    r.w = (a0.w + a1.w) + (a2.w + a3.w);

    __shared__ float4 red[4][64];
    red[sg][q] = r;
    __syncthreads();
    if (t < 64) {
        const float4 u0 = red[0][q], u1 = red[1][q], u2 = red[2][q], u3 = red[3][q];
        float4 o;
        o.x = (u0.x + u1.x) + (u2.x + u3.x);
        o.y = (u0.y + u1.y) + (u2.y + u3.y);
        o.z = (u0.z + u1.z) + (u2.z + u3.z);
        o.w = (u0.w + u1.w) + (u2.w + u3.w);
        float* d = att + ((size_t)b * CC + 4 * q) * KK + k;
        d[0 * KK] = o.x;
        d[1 * KK] = o.y;
        d[2 * KK] = o.z;
        d[3 * KK] = o.w;
    }
}

// ---- K2: gate + apply (round-2 structure) ----
#define S2 8                 // hw splits
#define CT2 16               // channels per block
#define CHUNK24 (HW4 / S2)   // 512 float4

__global__ __launch_bounds__(256) void CGM_k2_apply(
    const float* __restrict__ feature,
    const float* __restrict__ gamma,
    const float* __restrict__ att,
    float* __restrict__ out)
{
    const int bI = blockIdx.x;
    const int ct = bI & 15;
    const int s  = (bI >> 4) & (S2 - 1);
    const int b  = bI >> 7;
    const int t  = threadIdx.x;
    const int c0 = ct * CT2;

    __shared__ float sgk[CT2 * KK];
    __shared__ float scale[CT2];

    // NOTE: CT2*KK = 304 > 256 threads — MUST be a strided loop, not `if`.
    for (int idx = t; idx < CT2 * KK; idx += 256) {
        const int c = idx / KK;
        const int k = idx - c * KK;
        const float a = att[(size_t)(b * CC + c0 + c) * KK + k];
        const float sig = 1.f / (1.f + __expf(-a));
        sgk[idx] = sig * gamma[k];
    }
    __syncthreads();

    if (t < CT2) {
        float ssum = 0.f;
#define ADDK(K) ssum += sgk[t * KK + (K)];
        FOR_K(ADDK)
#undef ADDK
        scale[t] = 1.f + ssum;
    }
    __syncthreads();

    const float4* f4 = (const float4*)feature + (size_t)(b * CC + c0) * HW4;
    float4*       o4 = (float4*)out           + (size_t)(b * CC + c0) * HW4;
    const int ibase = s * CHUNK24;
#pragma unroll
    for (int c = 0; c < CT2; ++c) {
        const float sc = scale[c];
#pragma unroll
        for (int r = 0; r < CHUNK24 / 256; ++r) {   // 2 iterations
            const int i = ibase + r * 256 + t;
            const float4 f = f4[(size_t)c * HW4 + i];
            float4 o;
            o.x = f.x * sc;
            o.y = f.y * sc;
            o.z = f.z * sc;
            o.w = f.w * sc;
            o4[(size_t)c * HW4 + i] = o;
        }
    }
}

extern "C" void kernel_launch(void* const* d_in, const int* in_sizes, int n_in,
                              void* d_out, int out_size, void* d_ws, size_t ws_size,
                              hipStream_t stream) {
    const float* feature = (const float*)d_in[0];
    const float* map_    = (const float*)d_in[1];
    const float* gamma   = (const float*)d_in[2];
    float* out           = (float*)d_out;
    float* att           = (float*)d_ws;   // BB*CC*KK*4 = 155,648 B

    const size_t att_bytes  = (size_t)BB * CC * KK * sizeof(float);
    const size_t part_off   = (att_bytes + 255) & ~(size_t)255;
    const size_t part_bytes = (size_t)KK * BB * NS * CC * sizeof(float); // 19,922,944 B
    const bool   split      = ws_size >= part_off + part_bytes;
    float* part = split ? (float*)((char*)d_ws + part_off) : nullptr;

    if (!split) {
        // att is re-poisoned to 0xAA before every launch — atomic fallback
        // needs it zeroed (hipMemsetAsync on stream is graph-capture safe).
        hipMemsetAsync(att, 0, att_bytes, stream);
    }

    const int grid1 = BB * NS;                // 1024
    CGM_k1_contract<<<grid1, 256, 0, stream>>>(feature, map_, att, part);

    if (split) {
        CGM_k1b_reduce<<<BB * KK, 256, 0, stream>>>(part, att);
    }

    const int grid2 = BB * S2 * (CC / CT2);   // 1024
    CGM_k2_apply<<<grid2, 256, 0, stream>>>(feature, gamma, att, out);
}

// Round 5
// 310.742 us; speedup vs baseline: 3.2186x; 2.0942x over previous
//
#include <hip/hip_runtime.h>
#include <math.h>

#define BB 8
#define CC 256
#define KK 19
#define HW 16384
#define HW4 4096            // HW / 4 (float4 units)

#define CHUNK4 32           // float4 per hw-chunk = 128 floats
#define NS (HW4 / CHUNK4)   // 128 chunks per batch

// ---- K1 history ----
// r1: thread-per-channel, map in LDS: 93 us. LDS-issue-bound (608 broadcast
//     ds_read_b128/wave) + MLP-starved + ~70 MB residual spill at VGPR=64.
// r2/r3: more channels/thread -> compiler kept the 64-VGPR budget through
//     launch_bounds AND waves_per_eu (SGPR moved, VGPR didn't) -> acc in
//     scratch -> 0.8-2.5 GB scratch traffic. Lesson: design INSIDE 64 VGPRs.
// r4: map->SGPR via s_load asm + feature->LDS via global_load_lds + k-split
//     across waves. COMPILE FAIL: map pointer derives from klo=(t>>6)*5 ->
//     divergence analysis marks it divergent -> "s" constraint got VGPRs.
// r5 (this): same structure; map base pointers forced wave-uniform via
//     readfirstlane on the 32-bit halves (per-wave, so each wave's own base).
//     mp = uniform + constant stays uniform -> s_load operands allocate.

typedef float f32x4 __attribute__((ext_vector_type(4)));

#define AS1C(p) ((const __attribute__((address_space(1))) void*)(p))
#define AS3(p)  ((__attribute__((address_space(3))) void*)(p))

// Per-wave uniform pointer: readfirstlane both halves. Safe because the
// value is wave-uniform by construction (w = t>>6 is constant in a wave).
static __device__ __forceinline__ const float* uniform_ptr(const float* p) {
    unsigned long long u = (unsigned long long)p;
    unsigned lo = __builtin_amdgcn_readfirstlane((unsigned)u);
    unsigned hi = __builtin_amdgcn_readfirstlane((unsigned)(u >> 32));
    return (const float*)(((unsigned long long)hi << 32) | lo);
}

// 5 wave-uniform map rows (k-group) for one hw position -> 20 SGPRs.
// Offsets are k*HW*4 B = k*0x10000. Wait is inside the asm block, so every
// consumer of m0..m4 is dependency-ordered after completion.
#define MAP_LOAD5(MP, MP4)                                              \
    asm volatile(                                                        \
        "s_load_dwordx4 %[r0], %[p], 0x0\n\t"                            \
        "s_load_dwordx4 %[r1], %[p], 0x10000\n\t"                        \
        "s_load_dwordx4 %[r2], %[p], 0x20000\n\t"                        \
        "s_load_dwordx4 %[r3], %[p], 0x30000\n\t"                        \
        "s_load_dwordx4 %[r4], %[q], 0x0\n\t"                            \
        "s_waitcnt lgkmcnt(0)"                                           \
        : [r0]"=&s"(m0), [r1]"=&s"(m1), [r2]"=&s"(m2),                   \
          [r3]"=&s"(m3), [r4]"=&s"(m4)                                   \
        : [p]"s"(MP), [q]"s"(MP4))

#define FMAC(AV, MV, FV)                                                 \
    AV += FV.x * MV.x; AV += FV.y * MV.y; AV += FV.z * MV.z; AV += FV.w * MV.w;

__global__ __launch_bounds__(256) void CGM_k1_contract(
    const float* __restrict__ feature,
    const float* __restrict__ map_,
    float* __restrict__ att,        // fallback target (pre-zeroed)
    float* __restrict__ part)       // [KK][BB][NS][CC] partials, or nullptr
{
    const int bI   = blockIdx.x;            // ((b*NS + s) << 1) | half
    const int half = bI & 1;                // channel half: c in [half*128, +128)
    const int s    = (bI >> 1) & (NS - 1);
    const int b    = bI >> 8;
    const int t    = threadIdx.x;
    const int l    = t & 63;
    const int w    = t >> 6;                // wave id 0..3 -> k-group

    // 2 x 16 KB: tile = [128 ch][8 float4], double-buffered.
    __shared__ float4 buf[2][1024];

    const int klo = w * 5;                  // 0,5,10,15
    // Wave-uniform map bases (k-group row 0 and row 4) for this chunk.
    const float* mw_raw = map_ + (size_t)b * KK * HW + (size_t)klo * HW
                        + (size_t)s * (CHUNK4 * 4);
    // 5th row: k=klo+4, except wave 3 re-loads k=18 (dup, never stored).
    const size_t k4off = (size_t)((w == 3) ? 3 : 4) * HW;
    const float* mw  = uniform_ptr(mw_raw);
    const float* m4b = uniform_ptr(mw_raw + k4off);

    const float4* fbase = (const float4*)feature
                        + ((size_t)b * CC + half * 128) * HW4 + s * CHUNK4;

    // Stage tile JT into buf[BUFIDX]: linear LDS dest (wave-uniform base +
    // lane*16) + inverse-swizzled global source. 4 issues/thread, VGPR-free.
#define STAGE(BUFIDX, JT) do {                                           \
    _Pragma("unroll")                                                    \
    for (int q = 0; q < 4; ++q) {                                        \
        const int slot = q * 256 + t;                                    \
        const int ch   = slot >> 3;                                      \
        const int js   = slot & 7;                                       \
        const float4* g = fbase + (size_t)ch * HW4                       \
                        + (JT) * 8 + (js ^ (ch & 7));                    \
        __builtin_amdgcn_global_load_lds(AS1C(g),                        \
            AS3(&buf[BUFIDX][slot]), 16, 0, 0);                          \
    }                                                                    \
} while (0)

    float A00 = 0.f, A01 = 0.f, A02 = 0.f, A03 = 0.f, A04 = 0.f;  // c = l
    float A10 = 0.f, A11 = 0.f, A12 = 0.f, A13 = 0.f, A14 = 0.f;  // c = 64+l

    // Compute tile JT out of buf[BUFIDX]: per j, 5 SGPR map rows feed
    // 2 swizzled ds_read_b128 (c-rows l and 64+l) and 40 FMAs.
    // Swizzle check: LDS[ch][js] = G[ch][js^(ch&7)] (staged), read
    // LDS[l][j^(l&7)] = G[l][j]. Consecutive 8 lanes -> 8 distinct
    // bank-groups -> conflict-free.
#define COMPUTE(BUFIDX, JT) do {                                         \
    const float4* bc = buf[BUFIDX];                                      \
    _Pragma("unroll")                                                    \
    for (int j = 0; j < 8; ++j) {                                        \
        const float* mp  = mw  + (size_t)((JT) * 8 + j) * 4;             \
        const float* mp4 = m4b + (size_t)((JT) * 8 + j) * 4;             \
        f32x4 m0, m1, m2, m3, m4;                                        \
        MAP_LOAD5(mp, mp4);                                              \
        const float4 f0 = bc[(size_t)l * 8 + (j ^ (l & 7))];             \
        const float4 f1 = bc[(size_t)(64 + l) * 8 + (j ^ (l & 7))];      \
        FMAC(A00, m0, f0) FMAC(A01, m1, f0) FMAC(A02, m2, f0)            \
        FMAC(A03, m3, f0) FMAC(A04, m4, f0)                              \
        FMAC(A10, m0, f1) FMAC(A11, m1, f1) FMAC(A12, m2, f1)            \
        FMAC(A13, m3, f1) FMAC(A14, m4, f1)                              \
    }                                                                    \
} while (0)

    // 2-phase pipeline over the 4 j-tiles. STAGE(next) is issued before
    // COMPUTE(cur); __syncthreads' implicit vmcnt(0) drain comes after the
    // compute, so the staging loads fly underneath it.
    STAGE(0, 0); __syncthreads();
    STAGE(1, 1); COMPUTE(0, 0); __syncthreads();
    STAGE(0, 2); COMPUTE(1, 1); __syncthreads();
    STAGE(1, 3); COMPUTE(0, 2); __syncthreads();
    COMPUTE(1, 3);

#undef STAGE
#undef COMPUTE

    const int cbase = half * 128 + l;       // + 0 / +64 for the two c-rows
    if (part) {
        // part[k][b][s][c]: per k one coalesced 256 B store per c-row.
#define STK(KI, A0v, A1v) if (klo + (KI) < KK) {                         \
        float* d = part + ((size_t)((klo + (KI)) * BB + b) * NS + s) * CC \
                 + cbase;                                                \
        d[0] = A0v; d[64] = A1v; }
        STK(0, A00, A10) STK(1, A01, A11) STK(2, A02, A12)
        STK(3, A03, A13) STK(4, A04, A14)
#undef STK
    } else {
        // Fallback: fp32 atomics into pre-zeroed att.
#define STK(KI, A0v, A1v) if (klo + (KI) < KK) {                         \
        atomicAdd(&att[(size_t)(b * CC + cbase)      * KK + klo + (KI)], A0v); \
        atomicAdd(&att[(size_t)(b * CC + cbase + 64) * KK + klo + (KI)], A1v); }
        STK(0, A00, A10) STK(1, A01, A11) STK(2, A02, A12)
        STK(3, A03, A13) STK(4, A04, A14)
#undef STK
    }
}

// ---- K1b: fold the NS=128 hw-chunk partials into att (validated r1-r3). ----
__global__ __launch_bounds__(256) void CGM_k1b_reduce(
    const float* __restrict__ part,
    float* __restrict__ att)
{
    const int bk = blockIdx.x;      // b*KK + k
    const int b  = bk / KK;
    const int k  = bk - b * KK;
    const int t  = threadIdx.x;
    const int q  = t & 63;          // float4 column: channels 4q..4q+3
    const int sg = t >> 6;          // s quarter: 32 rows

    const float4* p4 = (const float4*)(part + (size_t)(k * BB + b) * NS * CC)
                     + (size_t)(sg * 32) * 64 + q;

    float4 a0 = {0.f, 0.f, 0.f, 0.f}, a1 = a0, a2 = a0, a3 = a0;
#pragma unroll 2
    for (int i = 0; i < 32; i += 4) {
        const float4 v0 = p4[(size_t)(i + 0) * 64];
        const float4 v1 = p4[(size_t)(i + 1) * 64];
        const float4 v2 = p4[(size_t)(i + 2) * 64];
        const float4 v3 = p4[(size_t)(i + 3) * 64];
        a0.x += v0.x; a0.y += v0.y; a0.z += v0.z; a0.w += v0.w;
        a1.x += v1.x; a1.y += v1.y; a1.z += v1.z; a1.w += v1.w;
        a2.x += v2.x; a2.y += v2.y; a2.z += v2.z; a2.w += v2.w;
        a3.x += v3.x; a3.y += v3.y; a3.z += v3.z; a3.w += v3.w;
    }
    float4 r;
    r.x = (a0.x + a1.x) + (a2.x + a3.x);
    r.y = (a0.y + a1.y) + (a2.y + a3.y);
    r.z = (a0.z + a1.z) + (a2.z + a3.z);
    r.w = (a0.w + a1.w) + (a2.w + a3.w);

    __shared__ float4 red[4][64];
    red[sg][q] = r;
    __syncthreads();
    if (t < 64) {
        const float4 u0 = red[0][q], u1 = red[1][q], u2 = red[2][q], u3 = red[3][q];
        float4 o;
        o.x = (u0.x + u1.x) + (u2.x + u3.x);
        o.y = (u0.y + u1.y) + (u2.y + u3.y);
        o.z = (u0.z + u1.z) + (u2.z + u3.z);
        o.w = (u0.w + u1.w) + (u2.w + u3.w);
        float* d = att + ((size_t)b * CC + 4 * q) * KK + k;
        d[0 * KK] = o.x;
        d[1 * KK] = o.y;
        d[2 * KK] = o.z;
        d[3 * KK] = o.w;
    }
}

// ---- K2: gate + apply (frozen since round 2) ----
#define S2 8                 // hw splits
#define CT2 16               // channels per block
#define CHUNK24 (HW4 / S2)   // 512 float4

#define FOR_K(OP) OP(0) OP(1) OP(2) OP(3) OP(4) OP(5) OP(6) OP(7) OP(8) OP(9) \
                  OP(10) OP(11) OP(12) OP(13) OP(14) OP(15) OP(16) OP(17) OP(18)

__global__ __launch_bounds__(256) void CGM_k2_apply(
    const float* __restrict__ feature,
    const float* __restrict__ gamma,
    const float* __restrict__ att,
    float* __restrict__ out)
{
    const int bI = blockIdx.x;
    const int ct = bI & 15;
    const int s  = (bI >> 4) & (S2 - 1);
    const int b  = bI >> 7;
    const int t  = threadIdx.x;
    const int c0 = ct * CT2;

    __shared__ float sgk[CT2 * KK];
    __shared__ float scale[CT2];

    // NOTE: CT2*KK = 304 > 256 threads — MUST be a strided loop, not `if`.
    for (int idx = t; idx < CT2 * KK; idx += 256) {
        const int c = idx / KK;
        const int k = idx - c * KK;
        const float a = att[(size_t)(b * CC + c0 + c) * KK + k];
        const float sig = 1.f / (1.f + __expf(-a));
        sgk[idx] = sig * gamma[k];
    }
    __syncthreads();

    if (t < CT2) {
        float ssum = 0.f;
#define ADDK(K) ssum += sgk[t * KK + (K)];
        FOR_K(ADDK)
#undef ADDK
        scale[t] = 1.f + ssum;
    }
    __syncthreads();

    const float4* f4 = (const float4*)feature + (size_t)(b * CC + c0) * HW4;
    float4*       o4 = (float4*)out           + (size_t)(b * CC + c0) * HW4;
    const int ibase = s * CHUNK24;
#pragma unroll
    for (int c = 0; c < CT2; ++c) {
        const float sc = scale[c];
#pragma unroll
        for (int r = 0; r < CHUNK24 / 256; ++r) {   // 2 iterations
            const int i = ibase + r * 256 + t;
            const float4 f = f4[(size_t)c * HW4 + i];
            float4 o;
            o.x = f.x * sc;
            o.y = f.y * sc;
            o.z = f.z * sc;
            o.w = f.w * sc;
            o4[(size_t)c * HW4 + i] = o;
        }
    }
}

extern "C" void kernel_launch(void* const* d_in, const int* in_sizes, int n_in,
                              void* d_out, int out_size, void* d_ws, size_t ws_size,
                              hipStream_t stream) {
    const float* feature = (const float*)d_in[0];
    const float* map_    = (const float*)d_in[1];
    const float* gamma   = (const float*)d_in[2];
    float* out           = (float*)d_out;
    float* att           = (float*)d_ws;   // BB*CC*KK*4 = 155,648 B

    const size_t att_bytes  = (size_t)BB * CC * KK * sizeof(float);
    const size_t part_off   = (att_bytes + 255) & ~(size_t)255;
    const size_t part_bytes = (size_t)KK * BB * NS * CC * sizeof(float); // 19,922,944 B
    const bool   split      = ws_size >= part_off + part_bytes;
    float* part = split ? (float*)((char*)d_ws + part_off) : nullptr;

    if (!split) {
        // att is re-poisoned to 0xAA before every launch — atomic fallback
        // needs it zeroed (hipMemsetAsync on stream is graph-capture safe).
        hipMemsetAsync(att, 0, att_bytes, stream);
    }

    const int grid1 = BB * NS * 2;            // 2048 (channel halves)
    CGM_k1_contract<<<grid1, 256, 0, stream>>>(feature, map_, att, part);

    if (split) {
        CGM_k1b_reduce<<<BB * KK, 256, 0, stream>>>(part, att);
    }

    const int grid2 = BB * S2 * (CC / CT2);   // 1024
    CGM_k2_apply<<<grid2, 256, 0, stream>>>(feature, gamma, att, out);
}

// Round 6
// 281.081 us; speedup vs baseline: 3.5582x; 1.1055x over previous
//
#include <hip/hip_runtime.h>
#include <math.h>

#define BB 8
#define CC 256
#define KK 19
#define HW 16384
#define HW4 4096            // HW / 4 (float4 units)

#define CHUNK4 32           // float4 per hw-chunk = 128 floats
#define NS (HW4 / CHUNK4)   // 128 chunks per batch

// ---- K1 history ----
// r1: thread-per-channel, map in LDS: 93 us. LDS-issue-bound + spill.
// r2/r3: more ch/thread -> compiler pinned 64 VGPRs -> acc in scratch ->
//     0.8-2.5 GB scratch traffic. Lesson: design INSIDE 64 VGPRs.
// r4: map->SGPR asm + feature->global_load_lds + k-split across waves.
//     Compile fail (divergent pointer for "s" constraint).
// r5: readfirstlane'd bases fixed the allocation. Result: VGPR=44, zero
//     scratch (WRITE=19.4MB exact), but 100 us: the asm's per-j
//     `s_waitcnt lgkmcnt(0)` full-drained SMEM+DS 64x/wave -> ~40us of
//     exposed scalar-cache latency and no ds_read pipelining.
// r6 (this): drop the asm. Map pointers become addrspace(4) (constant)
//     pointers built from the readfirstlane'd base -> backend selects
//     s_load_dwordx4 AND the compiler schedules them: batched per unrolled
//     tile, counted waits, hoisted above FMAs. One latency exposure per
//     ~8 j's instead of 64 full drains.

typedef float f32x4 __attribute__((ext_vector_type(4)));

#define AS1C(p) ((const __attribute__((address_space(1))) void*)(p))
#define AS3(p)  ((__attribute__((address_space(3))) void*)(p))

// Constant-AS vector pointer: uniform address + read-only memory -> s_load.
typedef const __attribute__((address_space(4))) f32x4* cvec4p;
#define CVEC4(p) ((cvec4p)(unsigned long long)(p))

// Per-wave uniform pointer: readfirstlane both halves. Safe because the
// value is wave-uniform by construction (w = t>>6 is constant in a wave).
static __device__ __forceinline__ const float* uniform_ptr(const float* p) {
    unsigned long long u = (unsigned long long)p;
    unsigned lo = __builtin_amdgcn_readfirstlane((unsigned)u);
    unsigned hi = __builtin_amdgcn_readfirstlane((unsigned)(u >> 32));
    return (const float*)(((unsigned long long)hi << 32) | lo);
}

#define FMAC(AV, MV, FV)                                                 \
    AV += FV.x * MV.x; AV += FV.y * MV.y; AV += FV.z * MV.z; AV += FV.w * MV.w;

__global__ __launch_bounds__(256) void CGM_k1_contract(
    const float* __restrict__ feature,
    const float* __restrict__ map_,
    float* __restrict__ att,        // fallback target (pre-zeroed)
    float* __restrict__ part)       // [KK][BB][NS][CC] partials, or nullptr
{
    const int bI   = blockIdx.x;            // ((b*NS + s) << 1) | half
    const int half = bI & 1;                // channel half: c in [half*128, +128)
    const int s    = (bI >> 1) & (NS - 1);
    const int b    = bI >> 8;
    const int t    = threadIdx.x;
    const int l    = t & 63;
    const int w    = t >> 6;                // wave id 0..3 -> k-group

    // 2 x 16 KB: tile = [128 ch][8 float4], double-buffered.
    __shared__ float4 buf[2][1024];

    const int klo = w * 5;                  // 0,5,10,15
    // Wave-uniform map bases for this chunk; k rows at +k*HW floats.
    const float* mw_raw = map_ + (size_t)b * KK * HW + (size_t)klo * HW
                        + (size_t)s * (CHUNK4 * 4);
    // 5th row: k=klo+4, except wave 3 re-loads k=18 (dup, never stored).
    const size_t k4off = (size_t)((w == 3) ? 3 : 4) * HW;
    const float* mw  = uniform_ptr(mw_raw);
    const float* m4b = uniform_ptr(mw_raw + k4off);

    // Constant-AS row pointers -> compiler-scheduled s_load_dwordx4.
    cvec4p cm0 = CVEC4(mw);
    cvec4p cm1 = CVEC4(mw + HW);
    cvec4p cm2 = CVEC4(mw + 2 * (size_t)HW);
    cvec4p cm3 = CVEC4(mw + 3 * (size_t)HW);
    cvec4p cm4 = CVEC4(m4b);

    const float4* fbase = (const float4*)feature
                        + ((size_t)b * CC + half * 128) * HW4 + s * CHUNK4;

    // Stage tile JT into buf[BUFIDX]: linear LDS dest (wave-uniform base +
    // lane*16) + inverse-swizzled global source. 4 issues/thread, VGPR-free.
#define STAGE(BUFIDX, JT) do {                                           \
    _Pragma("unroll")                                                    \
    for (int q = 0; q < 4; ++q) {                                        \
        const int slot = q * 256 + t;                                    \
        const int ch   = slot >> 3;                                      \
        const int js   = slot & 7;                                       \
        const float4* g = fbase + (size_t)ch * HW4                       \
                        + (JT) * 8 + (js ^ (ch & 7));                    \
        __builtin_amdgcn_global_load_lds(AS1C(g),                        \
            AS3(&buf[BUFIDX][slot]), 16, 0, 0);                          \
    }                                                                    \
} while (0)

    float A00 = 0.f, A01 = 0.f, A02 = 0.f, A03 = 0.f, A04 = 0.f;  // c = l
    float A10 = 0.f, A11 = 0.f, A12 = 0.f, A13 = 0.f, A14 = 0.f;  // c = 64+l

    // Compute tile JT out of buf[BUFIDX]: per j, 5 s_load_dwordx4 map rows
    // feed 2 swizzled ds_read_b128 (c-rows l and 64+l) and 40 FMAs.
    // Swizzle check: LDS[ch][js] = G[ch][js^(ch&7)] (staged), read
    // LDS[l][j^(l&7)] = G[l][j] -> conflict pattern is the 8-lane repeat
    // floor (~2 extra cyc/read, measured r5), acceptable.
#define COMPUTE(BUFIDX, JT) do {                                         \
    const float4* bc = buf[BUFIDX];                                      \
    _Pragma("unroll")                                                    \
    for (int j = 0; j < 8; ++j) {                                        \
        const int jj = (JT) * 8 + j;                                     \
        const f32x4 m0 = cm0[jj];                                        \
        const f32x4 m1 = cm1[jj];                                        \
        const f32x4 m2 = cm2[jj];                                        \
        const f32x4 m3 = cm3[jj];                                        \
        const f32x4 m4 = cm4[jj];                                        \
        const float4 f0 = bc[(size_t)l * 8 + (j ^ (l & 7))];             \
        const float4 f1 = bc[(size_t)(64 + l) * 8 + (j ^ (l & 7))];      \
        FMAC(A00, m0, f0) FMAC(A01, m1, f0) FMAC(A02, m2, f0)            \
        FMAC(A03, m3, f0) FMAC(A04, m4, f0)                              \
        FMAC(A10, m0, f1) FMAC(A11, m1, f1) FMAC(A12, m2, f1)            \
        FMAC(A13, m3, f1) FMAC(A14, m4, f1)                              \
    }                                                                    \
} while (0)

    // 2-phase pipeline over the 4 j-tiles. STAGE(next) is issued before
    // COMPUTE(cur); __syncthreads' implicit vmcnt(0) drain comes after the
    // compute, so the staging loads fly underneath it.
    STAGE(0, 0); __syncthreads();
    STAGE(1, 1); COMPUTE(0, 0); __syncthreads();
    STAGE(0, 2); COMPUTE(1, 1); __syncthreads();
    STAGE(1, 3); COMPUTE(0, 2); __syncthreads();
    COMPUTE(1, 3);

#undef STAGE
#undef COMPUTE

    const int cbase = half * 128 + l;       // + 0 / +64 for the two c-rows
    if (part) {
        // part[k][b][s][c]: per k one coalesced 256 B store per c-row.
#define STK(KI, A0v, A1v) if (klo + (KI) < KK) {                         \
        float* d = part + ((size_t)((klo + (KI)) * BB + b) * NS + s) * CC \
                 + cbase;                                                \
        d[0] = A0v; d[64] = A1v; }
        STK(0, A00, A10) STK(1, A01, A11) STK(2, A02, A12)
        STK(3, A03, A13) STK(4, A04, A14)
#undef STK
    } else {
        // Fallback: fp32 atomics into pre-zeroed att.
#define STK(KI, A0v, A1v) if (klo + (KI) < KK) {                         \
        atomicAdd(&att[(size_t)(b * CC + cbase)      * KK + klo + (KI)], A0v); \
        atomicAdd(&att[(size_t)(b * CC + cbase + 64) * KK + klo + (KI)], A1v); }
        STK(0, A00, A10) STK(1, A01, A11) STK(2, A02, A12)
        STK(3, A03, A13) STK(4, A04, A14)
#undef STK
    }
}

// ---- K1b: fold the NS=128 hw-chunk partials into att (validated r1-r5). ----
__global__ __launch_bounds__(256) void CGM_k1b_reduce(
    const float* __restrict__ part,
    float* __restrict__ att)
{
    const int bk = blockIdx.x;      // b*KK + k
    const int b  = bk / KK;
    const int k  = bk - b * KK;
    const int t  = threadIdx.x;
    const int q  = t & 63;          // float4 column: channels 4q..4q+3
    const int sg = t >> 6;          // s quarter: 32 rows

    const float4* p4 = (const float4*)(part + (size_t)(k * BB + b) * NS * CC)
                     + (size_t)(sg * 32) * 64 + q;

    float4 a0 = {0.f, 0.f, 0.f, 0.f}, a1 = a0, a2 = a0, a3 = a0;
#pragma unroll 2
    for (int i = 0; i < 32; i += 4) {
        const float4 v0 = p4[(size_t)(i + 0) * 64];
        const float4 v1 = p4[(size_t)(i + 1) * 64];
        const float4 v2 = p4[(size_t)(i + 2) * 64];
        const float4 v3 = p4[(size_t)(i + 3) * 64];
        a0.x += v0.x; a0.y += v0.y; a0.z += v0.z; a0.w += v0.w;
        a1.x += v1.x; a1.y += v1.y; a1.z += v1.z; a1.w += v1.w;
        a2.x += v2.x; a2.y += v2.y; a2.z += v2.z; a2.w += v2.w;
        a3.x += v3.x; a3.y += v3.y; a3.z += v3.z; a3.w += v3.w;
    }
    float4 r;
    r.x = (a0.x + a1.x) + (a2.x + a3.x);
    r.y = (a0.y + a1.y) + (a2.y + a3.y);
    r.z = (a0.z + a1.z) + (a2.z + a3.z);
    r.w = (a0.w + a1.w) + (a2.w + a3.w);

    __shared__ float4 red[4][64];
    red[sg][q] = r;
    __syncthreads();
    if (t < 64) {
        const float4 u0 = red[0][q], u1 = red[1][q], u2 = red[2][q], u3 = red[3][q];
        float4 o;
        o.x = (u0.x + u1.x) + (u2.x + u3.x);
        o.y = (u0.y + u1.y) + (u2.y + u3.y);
        o.z = (u0.z + u1.z) + (u2.z + u3.z);
        o.w = (u0.w + u1.w) + (u2.w + u3.w);
        float* d = att + ((size_t)b * CC + 4 * q) * KK + k;
        d[0 * KK] = o.x;
        d[1 * KK] = o.y;
        d[2 * KK] = o.z;
        d[3 * KK] = o.w;
    }
}

// ---- K2: gate + apply (frozen since round 2) ----
#define S2 8                 // hw splits
#define CT2 16               // channels per block
#define CHUNK24 (HW4 / S2)   // 512 float4

#define FOR_K(OP) OP(0) OP(1) OP(2) OP(3) OP(4) OP(5) OP(6) OP(7) OP(8) OP(9) \
                  OP(10) OP(11) OP(12) OP(13) OP(14) OP(15) OP(16) OP(17) OP(18)

__global__ __launch_bounds__(256) void CGM_k2_apply(
    const float* __restrict__ feature,
    const float* __restrict__ gamma,
    const float* __restrict__ att,
    float* __restrict__ out)
{
    const int bI = blockIdx.x;
    const int ct = bI & 15;
    const int s  = (bI >> 4) & (S2 - 1);
    const int b  = bI >> 7;
    const int t  = threadIdx.x;
    const int c0 = ct * CT2;

    __shared__ float sgk[CT2 * KK];
    __shared__ float scale[CT2];

    // NOTE: CT2*KK = 304 > 256 threads — MUST be a strided loop, not `if`.
    for (int idx = t; idx < CT2 * KK; idx += 256) {
        const int c = idx / KK;
        const int k = idx - c * KK;
        const float a = att[(size_t)(b * CC + c0 + c) * KK + k];
        const float sig = 1.f / (1.f + __expf(-a));
        sgk[idx] = sig * gamma[k];
    }
    __syncthreads();

    if (t < CT2) {
        float ssum = 0.f;
#define ADDK(K) ssum += sgk[t * KK + (K)];
        FOR_K(ADDK)
#undef ADDK
        scale[t] = 1.f + ssum;
    }
    __syncthreads();

    const float4* f4 = (const float4*)feature + (size_t)(b * CC + c0) * HW4;
    float4*       o4 = (float4*)out           + (size_t)(b * CC + c0) * HW4;
    const int ibase = s * CHUNK24;
#pragma unroll
    for (int c = 0; c < CT2; ++c) {
        const float sc = scale[c];
#pragma unroll
        for (int r = 0; r < CHUNK24 / 256; ++r) {   // 2 iterations
            const int i = ibase + r * 256 + t;
            const float4 f = f4[(size_t)c * HW4 + i];
            float4 o;
            o.x = f.x * sc;
            o.y = f.y * sc;
            o.z = f.z * sc;
            o.w = f.w * sc;
            o4[(size_t)c * HW4 + i] = o;
        }
    }
}

extern "C" void kernel_launch(void* const* d_in, const int* in_sizes, int n_in,
                              void* d_out, int out_size, void* d_ws, size_t ws_size,
                              hipStream_t stream) {
    const float* feature = (const float*)d_in[0];
    const float* map_    = (const float*)d_in[1];
    const float* gamma   = (const float*)d_in[2];
    float* out           = (float*)d_out;
    float* att           = (float*)d_ws;   // BB*CC*KK*4 = 155,648 B

    const size_t att_bytes  = (size_t)BB * CC * KK * sizeof(float);
    const size_t part_off   = (att_bytes + 255) & ~(size_t)255;
    const size_t part_bytes = (size_t)KK * BB * NS * CC * sizeof(float); // 19,922,944 B
    const bool   split      = ws_size >= part_off + part_bytes;
    float* part = split ? (float*)((char*)d_ws + part_off) : nullptr;

    if (!split) {
        // att is re-poisoned to 0xAA before every launch — atomic fallback
        // needs it zeroed (hipMemsetAsync on stream is graph-capture safe).
        hipMemsetAsync(att, 0, att_bytes, stream);
    }

    const int grid1 = BB * NS * 2;            // 2048 (channel halves)
    CGM_k1_contract<<<grid1, 256, 0, stream>>>(feature, map_, att, part);

    if (split) {
        CGM_k1b_reduce<<<BB * KK, 256, 0, stream>>>(part, att);
    }

    const int grid2 = BB * S2 * (CC / CT2);   // 1024
    CGM_k2_apply<<<grid2, 256, 0, stream>>>(feature, gamma, att, out);
}